// Round 1
// baseline (2801.357 us; speedup 1.0000x reference)
//
#include <hip/hip_runtime.h>
#include <hip/hip_bf16.h>

#define N_NODES 100000
#define N_EDGES 3200000
#define IN_F 256
#define OUT_F 128
#define NEG_SLOPE 0.2f

typedef short s16x8 __attribute__((ext_vector_type(8)));
typedef float f32x4 __attribute__((ext_vector_type(4)));

__device__ __forceinline__ unsigned short f2bf(float f) {
    __bf16 h = (__bf16)f;
    return __builtin_bit_cast(unsigned short, h);
}
__device__ __forceinline__ float bf2f(unsigned short u) {
    unsigned int x = ((unsigned int)u) << 16;
    return __builtin_bit_cast(float, x);
}

// Kernel 0: convert weight fp32 [OUT_F, IN_F] -> bf16 (ushort), same layout.
__global__ void wcvt_kernel(const float* __restrict__ w, unsigned short* __restrict__ wb) {
    int i = (blockIdx.x * blockDim.x + threadIdx.x) * 4;
    if (i >= OUT_F * IN_F) return;
    float4 v = *(const float4*)(w + i);
    ushort4 o;
    o.x = f2bf(v.x); o.y = f2bf(v.y); o.z = f2bf(v.z); o.w = f2bf(v.w);
    *(ushort4*)(wb + i) = o;
}

// Kernel 1: support = LeakyReLU(features @ W^T), stored as bf16.
// One wave computes 16 rows x 128 cols. Block = 4 waves = 64 rows.
__global__ __launch_bounds__(256) void gemm_kernel(
    const float* __restrict__ feat, const unsigned short* __restrict__ wb,
    unsigned short* __restrict__ sup) {
    int wid  = threadIdx.x >> 6;
    int lane = threadIdx.x & 63;
    long m0 = ((long)blockIdx.x * 4 + wid) * 16;
    if (m0 >= N_NODES) return;
    int quad = lane >> 4;        // 0..3
    int l16  = lane & 15;        // 0..15
    int kq   = quad * 8;         // k offset within 32-chunk

    const float* arow = feat + (m0 + l16) * IN_F + kq;

    f32x4 acc[8];
#pragma unroll
    for (int nt = 0; nt < 8; ++nt) acc[nt] = (f32x4){0.f, 0.f, 0.f, 0.f};

#pragma unroll
    for (int k0 = 0; k0 < IN_F; k0 += 32) {
        float4 a0 = *(const float4*)(arow + k0);
        float4 a1 = *(const float4*)(arow + k0 + 4);
        s16x8 a;
        a[0] = (short)f2bf(a0.x); a[1] = (short)f2bf(a0.y);
        a[2] = (short)f2bf(a0.z); a[3] = (short)f2bf(a0.w);
        a[4] = (short)f2bf(a1.x); a[5] = (short)f2bf(a1.y);
        a[6] = (short)f2bf(a1.z); a[7] = (short)f2bf(a1.w);
        const unsigned short* wp = wb + l16 * IN_F + k0 + kq;
#pragma unroll
        for (int nt = 0; nt < 8; ++nt) {
            s16x8 b = *(const s16x8*)(wp + (long)nt * 16 * IN_F);
            acc[nt] = __builtin_amdgcn_mfma_f32_16x16x32_bf16(a, b, acc[nt], 0, 0, 0);
        }
    }

    // C/D layout: col = lane&15, row = quad*4 + reg
    int crow = (int)m0 + quad * 4;
#pragma unroll
    for (int nt = 0; nt < 8; ++nt) {
#pragma unroll
        for (int r = 0; r < 4; ++r) {
            float v = acc[nt][r];
            v = (v > 0.f) ? v : (NEG_SLOPE * v);
            sup[(long)(crow + r) * OUT_F + nt * 16 + l16] = f2bf(v);
        }
    }
}

// Kernel 2: out[r] += v_e * support[c_e]   (1 wave per edge, 2 cols per lane)
__global__ __launch_bounds__(256) void scatter_kernel(
    const unsigned short* __restrict__ sup, const float* __restrict__ vals,
    const int* __restrict__ rows, const int* __restrict__ cols,
    float* __restrict__ out) {
    int wid  = threadIdx.x >> 6;
    int lane = threadIdx.x & 63;
    long e = (long)blockIdx.x * 4 + wid;
    if (e >= N_EDGES) return;
    int   r = rows[e];
    int   c = cols[e];
    float v = vals[e];
    const unsigned short* sp = sup + (long)c * OUT_F + lane * 2;
    ushort2 s2 = *(const ushort2*)sp;
    float* op = out + (long)r * OUT_F + lane * 2;
    atomicAdd(op,     bf2f(s2.x) * v);
    atomicAdd(op + 1, bf2f(s2.y) * v);
}

extern "C" void kernel_launch(void* const* d_in, const int* in_sizes, int n_in,
                              void* d_out, int out_size, void* d_ws, size_t ws_size,
                              hipStream_t stream) {
    const float* feat  = (const float*)d_in[0];
    const float* w     = (const float*)d_in[1];
    const float* evals = (const float*)d_in[2];
    const int*   erows = (const int*)d_in[3];
    const int*   ecols = (const int*)d_in[4];
    float* out = (float*)d_out;

    unsigned short* wb  = (unsigned short*)d_ws;                       // 64 KB
    unsigned short* sup = (unsigned short*)((char*)d_ws + 65536);      // 25.6 MB

    hipMemsetAsync(d_out, 0, (size_t)N_NODES * OUT_F * sizeof(float), stream);

    wcvt_kernel<<<(OUT_F * IN_F / 4 + 255) / 256, 256, 0, stream>>>(w, wb);

    int gemm_blocks = (N_NODES / 16 + 3) / 4;   // 1563
    gemm_kernel<<<gemm_blocks, 256, 0, stream>>>(feat, wb, sup);

    long scat_blocks = (N_EDGES + 3) / 4;       // 800000
    scatter_kernel<<<scat_blocks, 256, 0, stream>>>(sup, evals, erows, ecols, out);
}

// Round 2
// 717.590 us; speedup vs baseline: 3.9038x; 3.9038x over previous
//
#include <hip/hip_runtime.h>
#include <hip/hip_bf16.h>

#define N_NODES 100000
#define N_EDGES 3200000
#define IN_F 256
#define OUT_F 128
#define NEG_SLOPE 0.2f

typedef short s16x8 __attribute__((ext_vector_type(8)));
typedef float f32x4 __attribute__((ext_vector_type(4)));

__device__ __forceinline__ unsigned short f2bf(float f) {
    __bf16 h = (__bf16)f;
    return __builtin_bit_cast(unsigned short, h);
}
__device__ __forceinline__ float bf2f(unsigned short u) {
    unsigned int x = ((unsigned int)u) << 16;
    return __builtin_bit_cast(float, x);
}

// ---------- Kernel 0: weight fp32 -> bf16 ----------
__global__ void wcvt_kernel(const float* __restrict__ w, unsigned short* __restrict__ wb) {
    int i = (blockIdx.x * blockDim.x + threadIdx.x) * 4;
    if (i >= OUT_F * IN_F) return;
    float4 v = *(const float4*)(w + i);
    ushort4 o;
    o.x = f2bf(v.x); o.y = f2bf(v.y); o.z = f2bf(v.z); o.w = f2bf(v.w);
    *(ushort4*)(wb + i) = o;
}

// ---------- Kernel 1: support = LeakyReLU(feat @ W^T) as bf16 ----------
__global__ __launch_bounds__(256) void gemm_kernel(
    const float* __restrict__ feat, const unsigned short* __restrict__ wb,
    unsigned short* __restrict__ sup) {
    int wid  = threadIdx.x >> 6;
    int lane = threadIdx.x & 63;
    long m0 = ((long)blockIdx.x * 4 + wid) * 16;
    if (m0 >= N_NODES) return;
    int quad = lane >> 4;
    int l16  = lane & 15;
    int kq   = quad * 8;

    const float* arow = feat + (m0 + l16) * IN_F + kq;

    f32x4 acc[8];
#pragma unroll
    for (int nt = 0; nt < 8; ++nt) acc[nt] = (f32x4){0.f, 0.f, 0.f, 0.f};

#pragma unroll
    for (int k0 = 0; k0 < IN_F; k0 += 32) {
        float4 a0 = *(const float4*)(arow + k0);
        float4 a1 = *(const float4*)(arow + k0 + 4);
        s16x8 a;
        a[0] = (short)f2bf(a0.x); a[1] = (short)f2bf(a0.y);
        a[2] = (short)f2bf(a0.z); a[3] = (short)f2bf(a0.w);
        a[4] = (short)f2bf(a1.x); a[5] = (short)f2bf(a1.y);
        a[6] = (short)f2bf(a1.z); a[7] = (short)f2bf(a1.w);
        const unsigned short* wp = wb + l16 * IN_F + k0 + kq;
#pragma unroll
        for (int nt = 0; nt < 8; ++nt) {
            s16x8 b = *(const s16x8*)(wp + (long)nt * 16 * IN_F);
            acc[nt] = __builtin_amdgcn_mfma_f32_16x16x32_bf16(a, b, acc[nt], 0, 0, 0);
        }
    }

    int crow = (int)m0 + quad * 4;
#pragma unroll
    for (int nt = 0; nt < 8; ++nt) {
#pragma unroll
        for (int r = 0; r < 4; ++r) {
            float v = acc[nt][r];
            v = (v > 0.f) ? v : (NEG_SLOPE * v);
            sup[(long)(crow + r) * OUT_F + nt * 16 + l16] = f2bf(v);
        }
    }
}

// ---------- CSR build ----------
__global__ __launch_bounds__(256) void hist_kernel(const int* __restrict__ rows,
                                                   int* __restrict__ counts) {
    int e = blockIdx.x * 256 + threadIdx.x;
    if (e >= N_EDGES) return;
    atomicAdd(&counts[rows[e]], 1);
}

// scan phase 1: per-256-block sums
__global__ __launch_bounds__(256) void scan1_kernel(const int* __restrict__ counts,
                                                    int* __restrict__ bsum) {
    __shared__ int s[256];
    int tid = threadIdx.x;
    int i = blockIdx.x * 256 + tid;
    int v = (i < N_NODES) ? counts[i] : 0;
    s[tid] = v;
    __syncthreads();
#pragma unroll
    for (int st = 128; st > 0; st >>= 1) {
        if (tid < st) s[tid] += s[tid + st];
        __syncthreads();
    }
    if (tid == 0) bsum[blockIdx.x] = s[0];
}

// scan phase 2: exclusive scan of block sums (nb <= 512), one block
__global__ __launch_bounds__(512) void scan2_kernel(int* __restrict__ bsum, int nb) {
    __shared__ int s[512];
    int tid = threadIdx.x;
    int v = (tid < nb) ? bsum[tid] : 0;
    s[tid] = v;
    __syncthreads();
    for (int off = 1; off < 512; off <<= 1) {
        int t = (tid >= off) ? s[tid - off] : 0;
        __syncthreads();
        s[tid] += t;
        __syncthreads();
    }
    if (tid < nb) bsum[tid] = s[tid] - v;   // exclusive
}

// scan phase 3: per-block exclusive scan + block offset -> offs, cursor
__global__ __launch_bounds__(256) void scan3_kernel(const int* __restrict__ counts,
                                                    const int* __restrict__ bsum,
                                                    int* __restrict__ offs,
                                                    int* __restrict__ cursor) {
    __shared__ int s[256];
    int tid = threadIdx.x;
    int i = blockIdx.x * 256 + tid;
    int v = (i < N_NODES) ? counts[i] : 0;
    s[tid] = v;
    __syncthreads();
    for (int off = 1; off < 256; off <<= 1) {
        int t = (tid >= off) ? s[tid - off] : 0;
        __syncthreads();
        s[tid] += t;
        __syncthreads();
    }
    int excl = s[tid] - v + bsum[blockIdx.x];
    if (i < N_NODES) { offs[i] = excl; cursor[i] = excl; }
}

// fill: scatter (col, val) into CSR slots
__global__ __launch_bounds__(256) void fill_kernel(const int* __restrict__ rows,
                                                   const int* __restrict__ cols,
                                                   const float* __restrict__ vals,
                                                   int* __restrict__ cursor,
                                                   uint2* __restrict__ ed) {
    int e = blockIdx.x * 256 + threadIdx.x;
    if (e >= N_EDGES) return;
    int r = rows[e];
    int pos = atomicAdd(&cursor[r], 1);
    uint2 d;
    d.x = (unsigned)cols[e];
    d.y = __builtin_bit_cast(unsigned, vals[e]);
    ed[pos] = d;
}

// ---------- Kernel 2: per-row gather-accumulate (atomic-free) ----------
__global__ __launch_bounds__(256) void gather_kernel(
    const uint2* __restrict__ ed, const int* __restrict__ offs,
    const int* __restrict__ counts, const unsigned short* __restrict__ sup,
    float* __restrict__ out) {
    int wid  = threadIdx.x >> 6;
    int lane = threadIdx.x & 63;
    int row = blockIdx.x * 4 + wid;
    if (row >= N_NODES) return;
    int start = offs[row];
    int n = counts[row];
    const uint2* p = ed + start;

    float a0 = 0.f, a1 = 0.f;
    int i = 0;
    for (; i + 4 <= n; i += 4) {
        uint2 e0 = p[i], e1 = p[i + 1], e2 = p[i + 2], e3 = p[i + 3];
        ushort2 s0 = *(const ushort2*)(sup + (long)e0.x * OUT_F + lane * 2);
        ushort2 s1 = *(const ushort2*)(sup + (long)e1.x * OUT_F + lane * 2);
        ushort2 s2 = *(const ushort2*)(sup + (long)e2.x * OUT_F + lane * 2);
        ushort2 s3 = *(const ushort2*)(sup + (long)e3.x * OUT_F + lane * 2);
        float v0 = __builtin_bit_cast(float, e0.y);
        float v1 = __builtin_bit_cast(float, e1.y);
        float v2 = __builtin_bit_cast(float, e2.y);
        float v3 = __builtin_bit_cast(float, e3.y);
        a0 += v0 * bf2f(s0.x); a1 += v0 * bf2f(s0.y);
        a0 += v1 * bf2f(s1.x); a1 += v1 * bf2f(s1.y);
        a0 += v2 * bf2f(s2.x); a1 += v2 * bf2f(s2.y);
        a0 += v3 * bf2f(s3.x); a1 += v3 * bf2f(s3.y);
    }
    for (; i < n; ++i) {
        uint2 e0 = p[i];
        ushort2 s0 = *(const ushort2*)(sup + (long)e0.x * OUT_F + lane * 2);
        float v0 = __builtin_bit_cast(float, e0.y);
        a0 += v0 * bf2f(s0.x); a1 += v0 * bf2f(s0.y);
    }
    float* op = out + (long)row * OUT_F + lane * 2;
    op[0] = a0;
    op[1] = a1;
}

extern "C" void kernel_launch(void* const* d_in, const int* in_sizes, int n_in,
                              void* d_out, int out_size, void* d_ws, size_t ws_size,
                              hipStream_t stream) {
    const float* feat  = (const float*)d_in[0];
    const float* w     = (const float*)d_in[1];
    const float* evals = (const float*)d_in[2];
    const int*   erows = (const int*)d_in[3];
    const int*   ecols = (const int*)d_in[4];
    float* out = (float*)d_out;

    // workspace layout (all 256B-aligned)
    char* p = (char*)d_ws;
    unsigned short* wb  = (unsigned short*)p;            p += 65536;               // 64 KB
    unsigned short* sup = (unsigned short*)p;            p += (size_t)N_NODES * OUT_F * 2;  // 25.6 MB
    int* counts = (int*)p;                               p += (size_t)N_NODES * 4 + 256;
    int* offs   = (int*)p;                               p += (size_t)N_NODES * 4 + 256;
    int* cursor = (int*)p;                               p += (size_t)N_NODES * 4 + 256;
    int* bsum   = (int*)p;                               p += 4096;
    uint2* ed   = (uint2*)p;                             // 25.6 MB

    hipMemsetAsync(counts, 0, (size_t)N_NODES * 4, stream);

    wcvt_kernel<<<(OUT_F * IN_F / 4 + 255) / 256, 256, 0, stream>>>(w, wb);

    int gemm_blocks = (N_NODES / 16 + 3) / 4;
    gemm_kernel<<<gemm_blocks, 256, 0, stream>>>(feat, wb, sup);

    int eblocks = (N_EDGES + 255) / 256;
    hist_kernel<<<eblocks, 256, 0, stream>>>(erows, counts);

    int nb = (N_NODES + 255) / 256;   // 391
    scan1_kernel<<<nb, 256, 0, stream>>>(counts, bsum);
    scan2_kernel<<<1, 512, 0, stream>>>(bsum, nb);
    scan3_kernel<<<nb, 256, 0, stream>>>(counts, bsum, offs, cursor);

    fill_kernel<<<eblocks, 256, 0, stream>>>(erows, ecols, evals, cursor, ed);

    int gblocks = (N_NODES + 3) / 4;   // 25000
    gather_kernel<<<gblocks, 256, 0, stream>>>(ed, offs, counts, sup, out);
}